// Round 5
// baseline (331.711 us; speedup 1.0000x reference)
//
#include <hip/hip_runtime.h>

// Masked BCE: cost = sum(t==1 ? -log(p) : t==0 ? -log(1-p) : 0) / count(t<=1)
//
// R5: rolling register window, prefetch distance DEPTH=4 (8 loads / 8 KB in
// flight per wave continuously). Straight-line consume-slot-then-refill-slot
// order so compiler-inserted waitcnts are fine-grained (vmcnt(~8)), never a
// full drain. Grid 2000x256: n4 = 10,240,000 = 20 * 512,000 exactly ->
// uniform 20 iterations/thread, no tail on the bench shape.

#define GRID_BLOCKS 2000
#define BLOCK 256
#define DEPTH 4

__global__ __launch_bounds__(BLOCK) void bce_reduce_kernel(
    const float* __restrict__ prob,
    const int* __restrict__ tgt,
    float* __restrict__ part_sum,        // [GRID_BLOCKS]
    unsigned int* __restrict__ part_cnt, // [GRID_BLOCKS]
    int n)
{
    const int tid = blockIdx.x * BLOCK + threadIdx.x;
    const int S   = GRID_BLOCKS * BLOCK;   // 512,000
    const int n4  = n >> 2;

    const float4* __restrict__ p4 = (const float4*)prob;
    const int4*   __restrict__ t4 = (const int4*)tgt;

    float        lsum = 0.0f;
    unsigned int lcnt = 0u;

    #define ACC(P, T)                                   \
    {                                                   \
        float v = ((T) == 1) ? (P) : 1.0f - (P);        \
        bool  c = (unsigned)(T) <= 1u;                  \
        float l = -__logf(v);                           \
        lsum += c ? l : 0.0f;                           \
        lcnt += c ? 1u : 0u;                            \
    }
    #define ACC4(P, T) ACC((P).x,(T).x) ACC((P).y,(T).y) ACC((P).z,(T).z) ACC((P).w,(T).w)

    const int iters = n4 / S;

    if ((n4 % S) == 0 && iters >= DEPTH) {
        // fast path: uniform iteration count, rolling 4-slot register window
        float4 P[DEPTH];
        int4   T[DEPTH];

        #pragma unroll
        for (int k = 0; k < DEPTH; ++k) {
            P[k] = p4[tid + k * S];
            T[k] = t4[tid + k * S];
        }

        int r = DEPTH;
        for (; r + DEPTH <= iters; r += DEPTH) {
            #pragma unroll
            for (int k = 0; k < DEPTH; ++k) {
                float4 p = P[k];
                int4   t = T[k];
                // refill slot k (prefetch distance DEPTH) BEFORE computing,
                // so 8 loads stay outstanding through the ACC work
                P[k] = p4[tid + (r + k) * S];
                T[k] = t4[tid + (r + k) * S];
                ACC4(p, t)
            }
        }
        // leftover full rounds (iters not multiple of DEPTH): consume window,
        // then plain loop for the rest
        #pragma unroll
        for (int k = 0; k < DEPTH; ++k) {
            ACC4(P[k], T[k])
        }
        for (int i = tid + r * S; i < n4; i += S) {
            float4 p = p4[i];
            int4   t = t4[i];
            ACC4(p, t)
        }
    } else {
        // generic path
        for (int i = tid; i < n4; i += S) {
            float4 p = p4[i];
            int4   t = t4[i];
            ACC4(p, t)
        }
    }

    // scalar tail (n % 4 != 0)
    for (int k = (n4 << 2) + tid; k < n; k += S) {
        float p = prob[k];
        int   t = tgt[k];
        ACC(p, t)
    }

    // wave-64 reduction
    #pragma unroll
    for (int off = 32; off > 0; off >>= 1) {
        lsum += __shfl_down(lsum, off, 64);
        lcnt += __shfl_down(lcnt, off, 64);
    }

    // cross-wave via LDS (4 waves)
    __shared__ float        s_sum[4];
    __shared__ unsigned int s_cnt[4];
    const int lane = threadIdx.x & 63;
    const int wave = threadIdx.x >> 6;
    if (lane == 0) { s_sum[wave] = lsum; s_cnt[wave] = lcnt; }
    __syncthreads();
    if (threadIdx.x == 0) {
        part_sum[blockIdx.x] = s_sum[0] + s_sum[1] + s_sum[2] + s_sum[3];
        part_cnt[blockIdx.x] = s_cnt[0] + s_cnt[1] + s_cnt[2] + s_cnt[3];
    }
}

__global__ __launch_bounds__(BLOCK) void bce_finalize_kernel(
    const float* __restrict__ part_sum,
    const unsigned int* __restrict__ part_cnt,
    float* __restrict__ out)
{
    float        lsum = 0.0f;
    unsigned int lcnt = 0u;
    for (int i = threadIdx.x; i < GRID_BLOCKS; i += BLOCK) {
        lsum += part_sum[i];
        lcnt += part_cnt[i];
    }
    #pragma unroll
    for (int off = 32; off > 0; off >>= 1) {
        lsum += __shfl_down(lsum, off, 64);
        lcnt += __shfl_down(lcnt, off, 64);
    }
    __shared__ float        s_sum[4];
    __shared__ unsigned int s_cnt[4];
    const int lane = threadIdx.x & 63;
    const int wave = threadIdx.x >> 6;
    if (lane == 0) { s_sum[wave] = lsum; s_cnt[wave] = lcnt; }
    __syncthreads();
    if (threadIdx.x == 0) {
        float        bsum = s_sum[0] + s_sum[1] + s_sum[2] + s_sum[3];
        unsigned int bcnt = s_cnt[0] + s_cnt[1] + s_cnt[2] + s_cnt[3];
        out[0] = bsum / (float)bcnt;
    }
}

extern "C" void kernel_launch(void* const* d_in, const int* in_sizes, int n_in,
                              void* d_out, int out_size, void* d_ws, size_t ws_size,
                              hipStream_t stream) {
    const float* prob = (const float*)d_in[0];
    const int*   tgt  = (const int*)d_in[1];
    float*       out  = (float*)d_out;

    const int n = in_sizes[0];

    float*        part_sum = (float*)d_ws;
    unsigned int* part_cnt = (unsigned int*)((char*)d_ws + GRID_BLOCKS * sizeof(float));

    bce_reduce_kernel<<<GRID_BLOCKS, BLOCK, 0, stream>>>(prob, tgt, part_sum, part_cnt, n);
    bce_finalize_kernel<<<1, BLOCK, 0, stream>>>(part_sum, part_cnt, out);
}

// Round 6
// 327.643 us; speedup vs baseline: 1.0124x; 1.0124x over previous
//
#include <hip/hip_runtime.h>

// Masked BCE: cost = sum(t==1 ? -log(p) : t==0 ? -log(1-p) : 0) / count(t<=1)
//
// R6: split-path streaming to test whether the global_load_lds DMA queue and
// the vector-load MSHR queue are SEPARATE per-CU outstanding-request pools.
// prob -> plain dwordx4 register loads (MSHR pool), software-pipelined depth 1.
// tgt  -> 1 KB/wave global_load_lds DMA (DMA pool), wave-private double buffer.
// One manual s_waitcnt vmcnt(2) per iteration (VMEM retires in order ->
// both current-chunk ops done, the 2 just-issued prefetches stay in flight).

#define GRID_BLOCKS 2048
#define BLOCK 256
#define WAVES_PER_BLOCK 4
#define CHUNK_ELEMS 256   // per wave per chunk: 64 lanes x 4 elems (1 KB)

// s_waitcnt imm (gfx9): vmcnt[3:0] | expcnt<<4 | lgkmcnt<<8 | vmcnt[5:4]<<14
#define WAITCNT_VM(N) (((N) & 0xF) | (0x7 << 4) | (0xF << 8) | ((((N) >> 4) & 0x3) << 14))

typedef __attribute__((address_space(3))) void       lds_void_t;
typedef const __attribute__((address_space(1))) void gbl_void_t;

__global__ __launch_bounds__(BLOCK) void bce_reduce_kernel(
    const float* __restrict__ prob,
    const int* __restrict__ tgt,
    float* __restrict__ part_sum,        // [GRID_BLOCKS]
    unsigned int* __restrict__ part_cnt, // [GRID_BLOCKS]
    int nchunk,                          // n / CHUNK_ELEMS
    int n)
{
    // wave-private double buffers for tgt: [wave][buf] -> 1 KB
    __shared__ int lds_t[WAVES_PER_BLOCK][2][CHUNK_ELEMS];

    const int lane = threadIdx.x & 63;
    const int wave = threadIdx.x >> 6;
    const int wgid = blockIdx.x * WAVES_PER_BLOCK + wave;  // global wave id
    const int W    = GRID_BLOCKS * WAVES_PER_BLOCK;        // total waves (8192)

    float        lsum = 0.0f;
    unsigned int lcnt = 0u;

    #define ACC(P, T)                                   \
    {                                                   \
        float v = ((T) == 1) ? (P) : 1.0f - (P);        \
        bool  c = (unsigned)(T) <= 1u;                  \
        float l = -__logf(v);                           \
        lsum += c ? l : 0.0f;                           \
        lcnt += c ? 1u : 0u;                            \
    }
    #define ACC4(P, T) ACC((P).x,(T).x) ACC((P).y,(T).y) ACC((P).z,(T).z) ACC((P).w,(T).w)

    // DMA 1 KB of tgt chunk c into wave-private buffer b (one instruction).
    #define STAGE_T(c, b)                                                      \
        __builtin_amdgcn_global_load_lds(                                      \
            (gbl_void_t*)(tgt + (size_t)(c) * CHUNK_ELEMS + lane * 4),         \
            (lds_void_t*)&lds_t[wave][(b)][0], 16, 0, 0);

    // prob chunk c, this lane's float4
    #define PROB4(c) (*(const float4*)(prob + (size_t)(c) * CHUNK_ELEMS + lane * 4))

    int c   = wgid;
    int buf = 0;
    if (c < nchunk) {
        float4 P = PROB4(c);    // issue prob_c (vector load)
        STAGE_T(c, 0)           // issue dma_c
        while (c < nchunk) {
            const int cn = c + W;
            float4 Pn = P;
            if (cn < nchunk) {
                Pn = PROB4(cn);                               // issue prob_next
                STAGE_T(cn, buf ^ 1)                          // issue dma_next
                __builtin_amdgcn_s_waitcnt(WAITCNT_VM(2));    // prob_c + dma_c done
            } else {
                __builtin_amdgcn_s_waitcnt(WAITCNT_VM(0));    // final drain
            }
            const int4 t = *(const int4*)&lds_t[wave][buf][lane * 4];
            ACC4(P, t)
            P   = Pn;
            buf ^= 1;
            c   = cn;
        }
    }

    // generic tail: elements [nchunk*CHUNK_ELEMS, n) via plain loads
    {
        const int gtid = blockIdx.x * BLOCK + threadIdx.x;
        for (int k = nchunk * CHUNK_ELEMS + gtid; k < n; k += GRID_BLOCKS * BLOCK) {
            float p = prob[k];
            int   t = tgt[k];
            ACC(p, t)
        }
    }

    // wave-64 reduction
    #pragma unroll
    for (int off = 32; off > 0; off >>= 1) {
        lsum += __shfl_down(lsum, off, 64);
        lcnt += __shfl_down(lcnt, off, 64);
    }

    // cross-wave via LDS (4 waves); all wave DMAs drained above
    __shared__ float        s_sum[WAVES_PER_BLOCK];
    __shared__ unsigned int s_cnt[WAVES_PER_BLOCK];
    if (lane == 0) { s_sum[wave] = lsum; s_cnt[wave] = lcnt; }
    __syncthreads();
    if (threadIdx.x == 0) {
        part_sum[blockIdx.x] = s_sum[0] + s_sum[1] + s_sum[2] + s_sum[3];
        part_cnt[blockIdx.x] = s_cnt[0] + s_cnt[1] + s_cnt[2] + s_cnt[3];
    }
}

__global__ __launch_bounds__(BLOCK) void bce_finalize_kernel(
    const float* __restrict__ part_sum,
    const unsigned int* __restrict__ part_cnt,
    float* __restrict__ out)
{
    float        lsum = 0.0f;
    unsigned int lcnt = 0u;
    for (int i = threadIdx.x; i < GRID_BLOCKS; i += BLOCK) {
        lsum += part_sum[i];
        lcnt += part_cnt[i];
    }
    #pragma unroll
    for (int off = 32; off > 0; off >>= 1) {
        lsum += __shfl_down(lsum, off, 64);
        lcnt += __shfl_down(lcnt, off, 64);
    }
    __shared__ float        s_sum[4];
    __shared__ unsigned int s_cnt[4];
    const int lane = threadIdx.x & 63;
    const int wave = threadIdx.x >> 6;
    if (lane == 0) { s_sum[wave] = lsum; s_cnt[wave] = lcnt; }
    __syncthreads();
    if (threadIdx.x == 0) {
        float        bsum = s_sum[0] + s_sum[1] + s_sum[2] + s_sum[3];
        unsigned int bcnt = s_cnt[0] + s_cnt[1] + s_cnt[2] + s_cnt[3];
        out[0] = bsum / (float)bcnt;
    }
}

extern "C" void kernel_launch(void* const* d_in, const int* in_sizes, int n_in,
                              void* d_out, int out_size, void* d_ws, size_t ws_size,
                              hipStream_t stream) {
    const float* prob = (const float*)d_in[0];
    const int*   tgt  = (const int*)d_in[1];
    float*       out  = (float*)d_out;

    const int n      = in_sizes[0];
    const int nchunk = n / CHUNK_ELEMS;

    float*        part_sum = (float*)d_ws;
    unsigned int* part_cnt = (unsigned int*)((char*)d_ws + GRID_BLOCKS * sizeof(float));

    bce_reduce_kernel<<<GRID_BLOCKS, BLOCK, 0, stream>>>(prob, tgt, part_sum, part_cnt, nchunk, n);
    bce_finalize_kernel<<<1, BLOCK, 0, stream>>>(part_sum, part_cnt, out);
}

// Round 7
// 306.849 us; speedup vs baseline: 1.0810x; 1.0678x over previous
//
#include <hip/hip_runtime.h>

// Masked BCE: cost = sum(t==1 ? -log(p) : t==0 ? -log(1-p) : 0) / count(t<=1)
//
// R7: (a) DESCENDING 8 MB-window sweep — the harness's input restore leaves
// the most-recently-written ~256 MB L3-resident; reading high->low hits the
// freshest lines and should cut FETCH_SIZE from 164 MB to ~72-100 MB.
// (b) nontemporal (nt) loads — streaming policy, no L1/L2 retention.
// Grid 2000x256: n4 = 10,240,000 = 20 * 512,000 exactly -> uniform 20
// rounds/thread on the bench shape, no tail.

#define GRID_BLOCKS 2000
#define BLOCK 256

typedef __attribute__((ext_vector_type(4))) float f32x4;
typedef __attribute__((ext_vector_type(4))) int   i32x4;

__global__ __launch_bounds__(BLOCK) void bce_reduce_kernel(
    const float* __restrict__ prob,
    const int* __restrict__ tgt,
    float* __restrict__ part_sum,        // [GRID_BLOCKS]
    unsigned int* __restrict__ part_cnt, // [GRID_BLOCKS]
    int n)
{
    const int tid = blockIdx.x * BLOCK + threadIdx.x;
    const int S   = GRID_BLOCKS * BLOCK;   // 512,000
    const int n4  = n >> 2;

    const f32x4* __restrict__ p4 = (const f32x4*)prob;
    const i32x4* __restrict__ t4 = (const i32x4*)tgt;

    float        lsum = 0.0f;
    unsigned int lcnt = 0u;

    #define ACC(P, T)                                   \
    {                                                   \
        float v = ((T) == 1) ? (P) : 1.0f - (P);        \
        bool  c = (unsigned)(T) <= 1u;                  \
        float l = -__logf(v);                           \
        lsum += c ? l : 0.0f;                           \
        lcnt += c ? 1u : 0u;                            \
    }
    #define ACC4(P, T) ACC((P).x,(T).x) ACC((P).y,(T).y) ACC((P).z,(T).z) ACC((P).w,(T).w)

    const int iters = n4 / S;   // full rounds (20 on bench shape)

    // descending sweep over full rounds, 2 rounds per iteration (4 loads in flight)
    int k = iters - 1;
    for (; k >= 1; k -= 2) {
        f32x4 pa = __builtin_nontemporal_load(p4 + (tid + k * S));
        i32x4 ta = __builtin_nontemporal_load(t4 + (tid + k * S));
        f32x4 pb = __builtin_nontemporal_load(p4 + (tid + (k - 1) * S));
        i32x4 tb = __builtin_nontemporal_load(t4 + (tid + (k - 1) * S));
        ACC4(pa, ta)
        ACC4(pb, tb)
    }
    if (k == 0) {
        f32x4 p = __builtin_nontemporal_load(p4 + tid);
        i32x4 t = __builtin_nontemporal_load(t4 + tid);
        ACC4(p, t)
    }

    // leftover partial round (n4 % S != 0; not taken on bench shape)
    for (int i = tid + iters * S; i < n4; i += S) {
        f32x4 p = __builtin_nontemporal_load(p4 + i);
        i32x4 t = __builtin_nontemporal_load(t4 + i);
        ACC4(p, t)
    }

    // scalar tail (n % 4 != 0)
    for (int j = (n4 << 2) + tid; j < n; j += S) {
        float p = prob[j];
        int   t = tgt[j];
        ACC(p, t)
    }

    // wave-64 reduction
    #pragma unroll
    for (int off = 32; off > 0; off >>= 1) {
        lsum += __shfl_down(lsum, off, 64);
        lcnt += __shfl_down(lcnt, off, 64);
    }

    // cross-wave via LDS (4 waves)
    __shared__ float        s_sum[4];
    __shared__ unsigned int s_cnt[4];
    const int lane = threadIdx.x & 63;
    const int wave = threadIdx.x >> 6;
    if (lane == 0) { s_sum[wave] = lsum; s_cnt[wave] = lcnt; }
    __syncthreads();
    if (threadIdx.x == 0) {
        part_sum[blockIdx.x] = s_sum[0] + s_sum[1] + s_sum[2] + s_sum[3];
        part_cnt[blockIdx.x] = s_cnt[0] + s_cnt[1] + s_cnt[2] + s_cnt[3];
    }
}

__global__ __launch_bounds__(BLOCK) void bce_finalize_kernel(
    const float* __restrict__ part_sum,
    const unsigned int* __restrict__ part_cnt,
    float* __restrict__ out)
{
    float        lsum = 0.0f;
    unsigned int lcnt = 0u;
    for (int i = threadIdx.x; i < GRID_BLOCKS; i += BLOCK) {
        lsum += part_sum[i];
        lcnt += part_cnt[i];
    }
    #pragma unroll
    for (int off = 32; off > 0; off >>= 1) {
        lsum += __shfl_down(lsum, off, 64);
        lcnt += __shfl_down(lcnt, off, 64);
    }
    __shared__ float        s_sum[4];
    __shared__ unsigned int s_cnt[4];
    const int lane = threadIdx.x & 63;
    const int wave = threadIdx.x >> 6;
    if (lane == 0) { s_sum[wave] = lsum; s_cnt[wave] = lcnt; }
    __syncthreads();
    if (threadIdx.x == 0) {
        float        bsum = s_sum[0] + s_sum[1] + s_sum[2] + s_sum[3];
        unsigned int bcnt = s_cnt[0] + s_cnt[1] + s_cnt[2] + s_cnt[3];
        out[0] = bsum / (float)bcnt;
    }
}

extern "C" void kernel_launch(void* const* d_in, const int* in_sizes, int n_in,
                              void* d_out, int out_size, void* d_ws, size_t ws_size,
                              hipStream_t stream) {
    const float* prob = (const float*)d_in[0];
    const int*   tgt  = (const int*)d_in[1];
    float*       out  = (float*)d_out;

    const int n = in_sizes[0];

    float*        part_sum = (float*)d_ws;
    unsigned int* part_cnt = (unsigned int*)((char*)d_ws + GRID_BLOCKS * sizeof(float));

    bce_reduce_kernel<<<GRID_BLOCKS, BLOCK, 0, stream>>>(prob, tgt, part_sum, part_cnt, n);
    bce_finalize_kernel<<<1, BLOCK, 0, stream>>>(part_sum, part_cnt, out);
}